// Round 3
// baseline (386.538 us; speedup 1.0000x reference)
//
#include <hip/hip_runtime.h>
#include <hip/hip_bf16.h>

// out[e] = concat(node_states[src[e]], node_states[tgt[e]])
// One wave (64 lanes) per edge: row = 256 fp32 = 64 float4 -> one float4/lane.
// Lanes 0-31 cover the source half, lanes 32-63 the target half.
// R2->R3: dropped __builtin_nontemporal_store — harness fillBuffer proves
// plain dwordx4 store streams hit 6.3 TB/s through L2; nt path measured ~0.9 TB/s.

typedef float v4f __attribute__((ext_vector_type(4)));

__global__ __launch_bounds__(256) void NodePropagator_75110388073048_kernel(
    const v4f* __restrict__ ns,       // node_states as [N, 32] v4f
    const int* __restrict__ src32,    // edge_sources (int32 view)
    const int* __restrict__ tgt32,    // edge_targets (int32 view)
    v4f* __restrict__ out,            // [E, 64] v4f
    int nEdges)
{
    int tid  = blockIdx.x * blockDim.x + threadIdx.x;
    int e    = tid >> 6;              // edge index
    if (e >= nEdges) return;
    int lane = tid & 63;
    int half = lane >> 5;             // 0 = source half, 1 = target half
    int c    = lane & 31;             // v4f chunk within the half

    // --- index dtype probe (int64 vs int32), wave-uniform, cached loads ---
    bool is_i64 = (src32[1] == 0) & (src32[3] == 0) &
                  (src32[5] == 0) & (src32[7] == 0);

    const int* idxp = half ? tgt32 : src32;
    int row;
    if (is_i64) {
        row = (int)((const long long*)idxp)[e];
    } else {
        row = idxp[e];
    }

    v4f v = ns[row * 32 + c];
    out[e * 64 + lane] = v;           // plain store (was nontemporal)
}

extern "C" void kernel_launch(void* const* d_in, const int* in_sizes, int n_in,
                              void* d_out, int out_size, void* d_ws, size_t ws_size,
                              hipStream_t stream) {
    const v4f* ns  = (const v4f*)d_in[0];
    const int* src = (const int*)d_in[1];
    const int* tgt = (const int*)d_in[2];
    v4f*       out = (v4f*)d_out;

    int nEdges = in_sizes[1];                 // 320000
    long long totalThreads = (long long)nEdges * 64;   // one v4f per thread
    int block = 256;
    int grid  = (int)((totalThreads + block - 1) / block);

    NodePropagator_75110388073048_kernel<<<grid, block, 0, stream>>>(
        ns, src, tgt, out, nEdges);
}